// Round 5
// baseline (629.090 us; speedup 1.0000x reference)
//
#include <hip/hip_runtime.h>
#include <hip/hip_bf16.h>

// Problem: out = lecac_linear(relu(lecac_linear(x, W1, b1)), W2, b2)
//   x: [262144, 256] f32, W1: [512,256], b1: [512], W2: [256,512], b2: [256]
// R5: wave-specialized producer/consumer. R1-R4 plateaued at ~355us because
// per-CU LDS B-frag re-reads (~9K cyc/tile) + HBM + L2-weights + MFMA all ran
// SERIALLY in lockstep behind shared barriers. Now: waves 0-3 compute L1
// (x->h) while waves 4-7 concurrently compute L2 (h->out) one half-chunk
// behind; each SIMD hosts one of each, so all resource classes overlap.

typedef __attribute__((ext_vector_type(8))) short bf16x8;
typedef __attribute__((ext_vector_type(4))) float f32x4;
typedef __attribute__((ext_vector_type(4))) unsigned short us4;

#define D_IN 256
#define D_HID 512
#define D_OUT 256
#define BM 64
#define TILES 16

__device__ __forceinline__ unsigned short f2bf(float f) {
  union { __hip_bfloat16 h; unsigned short u; } c;
  c.h = __float2bfloat16(f);
  return c.u;
}

// ---- prep 1: deterministic f64 partial abs-sums (8 chunks per tensor) ------
__global__ void partial_abs_kernel(const float* __restrict__ W1,
                                   const float* __restrict__ W2,
                                   double* __restrict__ part) {
  const int b = blockIdx.x;                 // 0..15
  const float* W = (b < 8) ? W1 : W2;
  const float* p = W + (b & 7) * 16384;     // 131072 / 8
  double s = 0.0;
  for (int i = threadIdx.x; i < 16384; i += 1024) s += (double)fabsf(p[i]);
  __shared__ double red[1024];
  red[threadIdx.x] = s;
  __syncthreads();
  for (int st = 512; st > 0; st >>= 1) {
    if (threadIdx.x < st) red[threadIdx.x] += red[threadIdx.x + st];
    __syncthreads();
  }
  if (threadIdx.x == 0) part[b] = red[0];
}

// ---- prep 2: quantize codes (exact ints in bf16); finalizes scales inline --
__global__ void quant_kernel(const float* __restrict__ W1,
                             const float* __restrict__ W2,
                             const double* __restrict__ part,
                             unsigned short* __restrict__ w1c,
                             unsigned short* __restrict__ w2c,
                             float* __restrict__ fscales) {
  int idx = blockIdx.x * blockDim.x + threadIdx.x;  // 65536 float4 chunks
  bool is2 = idx >= 32768;
  const float4* src = is2 ? (const float4*)W2 : (const float4*)W1;
  us4* dst = is2 ? (us4*)w2c : (us4*)w1c;
  int i = is2 ? idx - 32768 : idx;
  const double* pp = part + (is2 ? 8 : 0);
  double sum = ((pp[0] + pp[1]) + (pp[2] + pp[3])) + ((pp[4] + pp[5]) + (pp[6] + pp[7]));
  double s = 1.47 * (sum / 131072.0) + 1e-8;
  if (idx == 0) {
    const double* q = part;
    double s0 = 1.47 * ((((q[0]+q[1])+(q[2]+q[3]))+((q[4]+q[5])+(q[6]+q[7]))) / 131072.0) + 1e-8;
    double s1 = 1.47 * ((((q[8]+q[9])+(q[10]+q[11]))+((q[12]+q[13])+(q[14]+q[15]))) / 131072.0) + 1e-8;
    fscales[0] = (float)s0;
    fscales[1] = (float)s1;
  }
  float4 v = src[i];
  us4 o;
  o.x = f2bf((float)fmin(fmax(rint((double)v.x / s), -2.0), 1.0));
  o.y = f2bf((float)fmin(fmax(rint((double)v.y / s), -2.0), 1.0));
  o.z = f2bf((float)fmin(fmax(rint((double)v.z / s), -2.0), 1.0));
  o.w = f2bf((float)fmin(fmax(rint((double)v.w / s), -2.0), 1.0));
  dst[i] = o;
}

// ---------------- fused specialized MLP kernel ------------------------------
// 256 blocks x 512 threads (8 waves), 1 block/CU, TILES=16 tiles each.
// L1-group (waves 0-3): wave w owns hidden rows [128w,128w+128), computed in
//   two half-chunks s=0/1 of 64 rows (c mod 128 in [64s,64s+64)).
// L2-group (waves 4-7): wave w owns out cols [64w,64w+64), consumes h
//   half-chunks one slot behind; also stages x(i+1) (regs->LDS) and stores out.
// hs compact layout: region s at col offset 256s, p = srcwave*64 + local;
// half-chunk (s,e-step) band c = 128*(e>>1)+64s+(e&1)*32.  All LDS tiles
// XOR-swizzled on 16B slots (^ row&7).  Raw s_barrier + lgkmcnt(0) only --
// x-loads / out-stores stay in flight across barriers.
__launch_bounds__(512, 2)
__global__ void fused_mlp(const float* __restrict__ x,
                          const float* __restrict__ b1,
                          const float* __restrict__ b2,
                          const unsigned short* __restrict__ w1c,
                          const unsigned short* __restrict__ w2c,
                          const float* __restrict__ fscales,
                          float* __restrict__ out) {
  __shared__ unsigned short xs[2][BM * D_IN];   // 2 x 32 KB bf16
  __shared__ unsigned short hs[BM * D_HID];     // 64 KB bf16
  const int t = threadIdx.x;
  const int lane = t & 63;
  const int wv = t >> 6;       // 0..7
  const int w = wv & 3;        // id within group
  const bool isL1 = wv < 4;
  const int l15 = lane & 15;
  const int g = (lane >> 4) & 3;
  const long tbase = (long)blockIdx.x * TILES;
  const float s1 = fscales[0], s2 = fscales[1];
  const f32x4 zero4 = {0.f, 0.f, 0.f, 0.f};

  f32x4 acc2[4][4];      // L2 persistent accumulator [mf][nf]
#pragma unroll
  for (int a = 0; a < 4; ++a)
#pragma unroll
    for (int b = 0; b < 4; ++b) acc2[a][b] = zero4;
  float4 xv[16];         // L2 x-prefetch registers

  // ---- L1 half-chunk: acc over K=256 for 64 hidden rows, write hs region s
  auto L1_SUB = [&](int i, int s) {
    const unsigned short* xb = xs[i & 1];
    const unsigned short* wp = w1c + (128 * w + 64 * s + l15) * 256 + g * 8;
    f32x4 acc1[4][4];
#pragma unroll
    for (int a = 0; a < 4; ++a)
#pragma unroll
      for (int b = 0; b < 4; ++b) acc1[a][b] = zero4;
    bf16x8 wA[2][4];
#pragma unroll
    for (int mf = 0; mf < 4; ++mf) {
      wA[0][mf] = *(const bf16x8*)(wp + mf * 4096);
      wA[1][mf] = *(const bf16x8*)(wp + mf * 4096 + 32);
    }
    bf16x8 bx[2][4];
#pragma unroll
    for (int nf = 0; nf < 4; ++nf) {
      int m = nf * 16 + l15;
      bx[0][nf] = *(const bf16x8*)&xb[m * 256 + (g ^ (m & 7)) * 8];
    }
#pragma unroll
    for (int kk = 0; kk < 8; ++kk) {
      bf16x8 a0 = wA[kk & 1][0], a1 = wA[kk & 1][1];
      bf16x8 a2 = wA[kk & 1][2], a3 = wA[kk & 1][3];
      if (kk + 2 < 8) {
#pragma unroll
        for (int mf = 0; mf < 4; ++mf)
          wA[kk & 1][mf] = *(const bf16x8*)(wp + mf * 4096 + (kk + 2) * 32);
      }
      if (kk + 1 < 8) {
#pragma unroll
        for (int nf = 0; nf < 4; ++nf) {
          int m = nf * 16 + l15;
          int slot = ((kk + 1) * 4 + g) ^ (m & 7);
          bx[(kk + 1) & 1][nf] = *(const bf16x8*)&xb[m * 256 + slot * 8];
        }
      }
#pragma unroll
      for (int nf = 0; nf < 4; ++nf) {
        acc1[0][nf] = __builtin_amdgcn_mfma_f32_16x16x32_bf16(a0, bx[kk & 1][nf], acc1[0][nf], 0, 0, 0);
        acc1[1][nf] = __builtin_amdgcn_mfma_f32_16x16x32_bf16(a1, bx[kk & 1][nf], acc1[1][nf], 0, 0, 0);
        acc1[2][nf] = __builtin_amdgcn_mfma_f32_16x16x32_bf16(a2, bx[kk & 1][nf], acc1[2][nf], 0, 0, 0);
        acc1[3][nf] = __builtin_amdgcn_mfma_f32_16x16x32_bf16(a3, bx[kk & 1][nf], acc1[3][nf], 0, 0, 0);
      }
    }
    // epilogue: h = relu(s1*acc1 + b1) -> hs region s (compact, swizzled)
#pragma unroll
    for (int mf = 0; mf < 4; ++mf) {
      int c = 128 * w + 64 * s + 16 * mf + 4 * g;
      float4 bb = *(const float4*)&b1[c];
      int q0 = s * 32 + w * 8 + 2 * mf + (g >> 1);
      int half = (g & 1) * 4;
#pragma unroll
      for (int nf = 0; nf < 4; ++nf) {
        int m = nf * 16 + l15;
        f32x4 a = acc1[mf][nf];
        us4 o;
        o.x = f2bf(fmaxf(s1 * a[0] + bb.x, 0.f));
        o.y = f2bf(fmaxf(s1 * a[1] + bb.y, 0.f));
        o.z = f2bf(fmaxf(s1 * a[2] + bb.z, 0.f));
        o.w = f2bf(fmaxf(s1 * a[3] + bb.w, 0.f));
        *(us4*)&hs[m * 512 + (q0 ^ (m & 7)) * 8 + half] = o;
      }
    }
  };

  // ---- L2 half-chunk: accumulate acc2 over hs region s (K=256)
  auto L2_SUB = [&](int s) {
    const unsigned short* wp2 = w2c + (64 * w + l15) * 512 + 64 * s + g * 8;
    bf16x8 wB[2][4];
#pragma unroll
    for (int mf = 0; mf < 4; ++mf) {
      wB[0][mf] = *(const bf16x8*)(wp2 + mf * 8192);            // e=0
      wB[1][mf] = *(const bf16x8*)(wp2 + mf * 8192 + 32);       // e=1
    }
    bf16x8 bh[2][4];
#pragma unroll
    for (int nf = 0; nf < 4; ++nf) {
      int m = nf * 16 + l15;
      int q0 = s * 32 + 0 * 4 + g;
      bh[0][nf] = *(const bf16x8*)&hs[m * 512 + (q0 ^ (m & 7)) * 8];
    }
#pragma unroll
    for (int e = 0; e < 8; ++e) {
      bf16x8 a0 = wB[e & 1][0], a1 = wB[e & 1][1];
      bf16x8 a2 = wB[e & 1][2], a3 = wB[e & 1][3];
      if (e + 2 < 8) {
        int e2 = e + 2;
        int off = 128 * (e2 >> 1) + (e2 & 1) * 32;
#pragma unroll
        for (int mf = 0; mf < 4; ++mf)
          wB[e & 1][mf] = *(const bf16x8*)(wp2 + mf * 8192 + off);
      }
      if (e + 1 < 8) {
#pragma unroll
        for (int nf = 0; nf < 4; ++nf) {
          int m = nf * 16 + l15;
          int q0 = s * 32 + (e + 1) * 4 + g;
          bh[(e + 1) & 1][nf] = *(const bf16x8*)&hs[m * 512 + (q0 ^ (m & 7)) * 8];
        }
      }
#pragma unroll
      for (int nf = 0; nf < 4; ++nf) {
        acc2[0][nf] = __builtin_amdgcn_mfma_f32_16x16x32_bf16(a0, bh[e & 1][nf], acc2[0][nf], 0, 0, 0);
        acc2[1][nf] = __builtin_amdgcn_mfma_f32_16x16x32_bf16(a1, bh[e & 1][nf], acc2[1][nf], 0, 0, 0);
        acc2[2][nf] = __builtin_amdgcn_mfma_f32_16x16x32_bf16(a2, bh[e & 1][nf], acc2[2][nf], 0, 0, 0);
        acc2[3][nf] = __builtin_amdgcn_mfma_f32_16x16x32_bf16(a3, bh[e & 1][nf], acc2[3][nf], 0, 0, 0);
      }
    }
  };

  auto EPI2 = [&](int i) {  // store out tile i, then clear acc2
    const long row0 = (tbase + i) * BM;
#pragma unroll
    for (int mf = 0; mf < 4; ++mf) {
      int n4 = 64 * w + 16 * mf + 4 * g;
      float4 bb = *(const float4*)&b2[n4];
#pragma unroll
      for (int nf = 0; nf < 4; ++nf) {
        int m = nf * 16 + l15;
        f32x4 a = acc2[mf][nf];
        float4 o;
        o.x = s2 * a[0] + bb.x;
        o.y = s2 * a[1] + bb.y;
        o.z = s2 * a[2] + bb.z;
        o.w = s2 * a[3] + bb.w;
        *(float4*)&out[(row0 + m) * D_OUT + n4] = o;
        acc2[mf][nf] = zero4;
      }
    }
  };

  // ---- prologue: all 512 threads stage xs[0] for tile 0
  {
    const float4* p = (const float4*)x + tbase * (BM * D_IN / 4);
#pragma unroll
    for (int j = 0; j < 8; ++j) {
      int chunk = j * 512 + t;
      int m = chunk >> 6, c4 = chunk & 63;
      float4 v = p[chunk];
      int slot = (c4 >> 1) ^ (m & 7);
      us4 o;
      o.x = f2bf(v.x); o.y = f2bf(v.y); o.z = f2bf(v.z); o.w = f2bf(v.w);
      *(us4*)&xs[0][m * 256 + slot * 8 + (c4 & 1) * 4] = o;
    }
  }
  __syncthreads();

  const int tl = t & 255;  // L2 lane index 0..255
  for (int i = 0; i < TILES; ++i) {
    // ---------- slot A ----------
    if (isL1) {
      L1_SUB(i, 0);                      // reads xs[i&1], writes hs region 0
    } else {
      if (i > 0) { L2_SUB(1); EPI2(i - 1); }   // reads hs region 1 (tile i-1)
      if (i + 1 < TILES) {               // issue x(i+1) loads (stay in flight)
        const float4* p = (const float4*)x + (tbase + i + 1) * (BM * D_IN / 4);
#pragma unroll
        for (int j = 0; j < 16; ++j) xv[j] = p[j * 256 + tl];
      }
    }
    asm volatile("s_waitcnt lgkmcnt(0)" ::: "memory");
    __builtin_amdgcn_s_barrier();
    // ---------- slot B ----------
    if (isL1) {
      L1_SUB(i, 1);                      // writes hs region 1
    } else {
      if (i + 1 < TILES) {               // stage xs[(i+1)&1] from xv
        unsigned short* xb = xs[(i + 1) & 1];
#pragma unroll
        for (int j = 0; j < 16; ++j) {
          int chunk = j * 256 + tl;
          int m = chunk >> 6, c4 = chunk & 63;
          int slot = (c4 >> 1) ^ (m & 7);
          us4 o;
          o.x = f2bf(xv[j].x); o.y = f2bf(xv[j].y);
          o.z = f2bf(xv[j].z); o.w = f2bf(xv[j].w);
          *(us4*)&xb[m * 256 + slot * 8 + (c4 & 1) * 4] = o;
        }
      }
      L2_SUB(0);                         // reads hs region 0 (tile i)
    }
    asm volatile("s_waitcnt lgkmcnt(0)" ::: "memory");
    __builtin_amdgcn_s_barrier();
  }
  // ---- epilogue: L2 finishes last tile (hs region 1 published by last barrier)
  if (!isL1) { L2_SUB(1); EPI2(TILES - 1); }
}

extern "C" void kernel_launch(void* const* d_in, const int* in_sizes, int n_in,
                              void* d_out, int out_size, void* d_ws, size_t ws_size,
                              hipStream_t stream) {
  const float* x  = (const float*)d_in[0];
  const float* W1 = (const float*)d_in[1];
  const float* b1 = (const float*)d_in[2];
  const float* W2 = (const float*)d_in[3];
  const float* b2 = (const float*)d_in[4];
  float* out = (float*)d_out;

  double* part = (double*)d_ws;
  float* fsc = (float*)((char*)d_ws + 128);
  unsigned short* w1c = (unsigned short*)((char*)d_ws + 1024);
  unsigned short* w2c = (unsigned short*)((char*)d_ws + 1024 + D_HID * D_IN * 2);

  int Brows = in_sizes[0] / D_IN;     // 262144
  int nblk = Brows / (BM * TILES);    // 256

  partial_abs_kernel<<<dim3(16), dim3(1024), 0, stream>>>(W1, W2, part);
  quant_kernel<<<dim3(256), dim3(256), 0, stream>>>(W1, W2, part, w1c, w2c, fsc);
  fused_mlp<<<dim3(nblk), dim3(512), 0, stream>>>(x, b1, b2, w1c, w2c, fsc, out);
}

// Round 6
// 481.544 us; speedup vs baseline: 1.3064x; 1.3064x over previous
//
#include <hip/hip_runtime.h>
#include <hip/hip_bf16.h>

// Problem: out = lecac_linear(relu(lecac_linear(x, W1, b1)), W2, b2)
//   x: [262144, 256] f32, W1: [512,256], b1: [512], W2: [256,512], b2: [256]
// R6: persistent kernel, WEIGHTS IN REGISTERS (loaded once per block), 8 fat
// waves. R1-R5 serialized HBM + LDS + L2-weight + MFMA streams (~53K cyc/tile);
// weights-in-regs deletes the L2 stream and its latency stalls, fat waves
// halve LDS B-frag re-reads, x prefetched 2 tiles deep with raw barriers.

typedef __attribute__((ext_vector_type(8))) short bf16x8;
typedef __attribute__((ext_vector_type(4))) float f32x4;
typedef __attribute__((ext_vector_type(4))) unsigned short us4;

#define D_IN 256
#define D_HID 512
#define D_OUT 256
#define BM 64
#define TILES 16

__device__ __forceinline__ unsigned short f2bf(float f) {
  union { __hip_bfloat16 h; unsigned short u; } c;
  c.h = __float2bfloat16(f);
  return c.u;
}

// ---- prep 1: deterministic f64 partial abs-sums (8 chunks per tensor) ------
__global__ void partial_abs_kernel(const float* __restrict__ W1,
                                   const float* __restrict__ W2,
                                   double* __restrict__ part) {
  const int b = blockIdx.x;                 // 0..15
  const float* W = (b < 8) ? W1 : W2;
  const float* p = W + (b & 7) * 16384;     // 131072 / 8
  double s = 0.0;
  for (int i = threadIdx.x; i < 16384; i += 1024) s += (double)fabsf(p[i]);
  __shared__ double red[1024];
  red[threadIdx.x] = s;
  __syncthreads();
  for (int st = 512; st > 0; st >>= 1) {
    if (threadIdx.x < st) red[threadIdx.x] += red[threadIdx.x + st];
    __syncthreads();
  }
  if (threadIdx.x == 0) part[b] = red[0];
}

// ---- prep 2: quantize codes (exact ints in bf16); finalizes scales inline --
__global__ void quant_kernel(const float* __restrict__ W1,
                             const float* __restrict__ W2,
                             const double* __restrict__ part,
                             unsigned short* __restrict__ w1c,
                             unsigned short* __restrict__ w2c,
                             float* __restrict__ fscales) {
  int idx = blockIdx.x * blockDim.x + threadIdx.x;  // 65536 float4 chunks
  bool is2 = idx >= 32768;
  const float4* src = is2 ? (const float4*)W2 : (const float4*)W1;
  us4* dst = is2 ? (us4*)w2c : (us4*)w1c;
  int i = is2 ? idx - 32768 : idx;
  const double* pp = part + (is2 ? 8 : 0);
  double sum = ((pp[0] + pp[1]) + (pp[2] + pp[3])) + ((pp[4] + pp[5]) + (pp[6] + pp[7]));
  double s = 1.47 * (sum / 131072.0) + 1e-8;
  if (idx == 0) {
    const double* q = part;
    double s0 = 1.47 * ((((q[0]+q[1])+(q[2]+q[3]))+((q[4]+q[5])+(q[6]+q[7]))) / 131072.0) + 1e-8;
    double s1 = 1.47 * ((((q[8]+q[9])+(q[10]+q[11]))+((q[12]+q[13])+(q[14]+q[15]))) / 131072.0) + 1e-8;
    fscales[0] = (float)s0;
    fscales[1] = (float)s1;
  }
  float4 v = src[i];
  us4 o;
  o.x = f2bf((float)fmin(fmax(rint((double)v.x / s), -2.0), 1.0));
  o.y = f2bf((float)fmin(fmax(rint((double)v.y / s), -2.0), 1.0));
  o.z = f2bf((float)fmin(fmax(rint((double)v.z / s), -2.0), 1.0));
  o.w = f2bf((float)fmin(fmax(rint((double)v.w / s), -2.0), 1.0));
  dst[i] = o;
}

// ---------------- fused persistent MLP kernel -------------------------------
// 256 blocks x 512 threads (8 waves), 1 block/CU, 16 tiles of 64 rows each.
// Wave wv holds W1 rows [64wv,64wv+64) (128 VGPR) and W2 rows [32wv,32wv+32)
// (128 VGPR) as resident MFMA A-fragments. Per tile: L1 -> bar -> epi1(+x
// stage/load) -> bar -> L2 -> out stores. Raw s_barrier + lgkmcnt(0) only.
__launch_bounds__(512, 2)
__global__ void fused_mlp(const float* __restrict__ x,
                          const float* __restrict__ b1,
                          const float* __restrict__ b2,
                          const unsigned short* __restrict__ w1c,
                          const unsigned short* __restrict__ w2c,
                          const float* __restrict__ fscales,
                          float* __restrict__ out) {
  __shared__ unsigned short xs[2][BM * D_IN];   // 2 x 32 KB bf16
  __shared__ unsigned short hs[BM * D_HID];     // 64 KB bf16
  const int t = threadIdx.x;
  const int lane = t & 63;
  const int wv = t >> 6;       // 0..7
  const int l15 = lane & 15;
  const int g = lane >> 4;     // 0..3
  const long tbase = (long)blockIdx.x * TILES;
  const float s1 = fscales[0], s2 = fscales[1];
  const f32x4 zero4 = {0.f, 0.f, 0.f, 0.f};

  // ---- resident weight fragments (loaded once; L2/L3-served, 512KB/block)
  bf16x8 w1r[4][8];   // [mf: 16-row block][kk: 32-k block]  = 128 VGPR
#pragma unroll
  for (int mf = 0; mf < 4; ++mf)
#pragma unroll
    for (int kk = 0; kk < 8; ++kk)
      w1r[mf][kk] = *(const bf16x8*)&w1c[(64 * wv + 16 * mf + l15) * 256 + kk * 32 + g * 8];
  bf16x8 w2r[2][16];  // [mf][kk] = 128 VGPR
#pragma unroll
  for (int mf = 0; mf < 2; ++mf)
#pragma unroll
    for (int kk = 0; kk < 16; ++kk)
      w2r[mf][kk] = *(const bf16x8*)&w2c[(32 * wv + 16 * mf + l15) * 512 + kk * 32 + g * 8];

  float4 xv[8];  // next-tile x prefetch (32 VGPR)

  auto loadxv = [&](long tile) {
    const float4* p = (const float4*)x + tile * 4096;
#pragma unroll
    for (int j = 0; j < 8; ++j) xv[j] = p[j * 512 + t];
  };
  auto stagex = [&](int buf) {  // xv -> xs[buf], XOR-swizzled (slot ^= row&7)
    unsigned short* xb = xs[buf];
#pragma unroll
    for (int j = 0; j < 8; ++j) {
      int chunk = j * 512 + t;
      int m = chunk >> 6, c4 = chunk & 63;
      int slot = (c4 >> 1) ^ (m & 7);
      us4 o;
      o.x = f2bf(xv[j].x); o.y = f2bf(xv[j].y);
      o.z = f2bf(xv[j].z); o.w = f2bf(xv[j].w);
      *(us4*)&xb[m * 256 + slot * 8 + (c4 & 1) * 4] = o;
    }
  };

  f32x4 acc1[4][4];
  f32x4 acc2[2][4];

  // ---- prologue: stage tile 0 directly, issue loads for tile 1
  loadxv(tbase);
  stagex(0);
  loadxv(tbase + 1);
  asm volatile("s_waitcnt lgkmcnt(0)" ::: "memory");
  __builtin_amdgcn_s_barrier();

  for (int i = 0; i < TILES; ++i) {
    // ================= L1: acc1 = W1r * xs[i&1]^T (K=256) =================
    const unsigned short* xb = xs[i & 1];
#pragma unroll
    for (int a = 0; a < 4; ++a)
#pragma unroll
      for (int b = 0; b < 4; ++b) acc1[a][b] = zero4;
    {
      bf16x8 bx[2][4];
#pragma unroll
      for (int nf = 0; nf < 4; ++nf) {
        int m = nf * 16 + l15;
        bx[0][nf] = *(const bf16x8*)&xb[m * 256 + (g ^ (m & 7)) * 8];
      }
#pragma unroll
      for (int kk = 0; kk < 8; ++kk) {
        if (kk + 1 < 8) {
#pragma unroll
          for (int nf = 0; nf < 4; ++nf) {
            int m = nf * 16 + l15;
            int slot = ((kk + 1) * 4 + g) ^ (m & 7);
            bx[(kk + 1) & 1][nf] = *(const bf16x8*)&xb[m * 256 + slot * 8];
          }
        }
#pragma unroll
        for (int nf = 0; nf < 4; ++nf) {
          acc1[0][nf] = __builtin_amdgcn_mfma_f32_16x16x32_bf16(w1r[0][kk], bx[kk & 1][nf], acc1[0][nf], 0, 0, 0);
          acc1[1][nf] = __builtin_amdgcn_mfma_f32_16x16x32_bf16(w1r[1][kk], bx[kk & 1][nf], acc1[1][nf], 0, 0, 0);
          acc1[2][nf] = __builtin_amdgcn_mfma_f32_16x16x32_bf16(w1r[2][kk], bx[kk & 1][nf], acc1[2][nf], 0, 0, 0);
          acc1[3][nf] = __builtin_amdgcn_mfma_f32_16x16x32_bf16(w1r[3][kk], bx[kk & 1][nf], acc1[3][nf], 0, 0, 0);
        }
      }
    }
    asm volatile("s_waitcnt lgkmcnt(0)" ::: "memory");
    __builtin_amdgcn_s_barrier();   // hs reads of L2(i-1) complete everywhere

    // ===== epi1: hs = relu(s1*acc1 + b1); stage xs[i+1]; issue x(i+2) ======
#pragma unroll
    for (int mf = 0; mf < 4; ++mf) {
      int cb = 64 * wv + 16 * mf + g * 4;
      float4 bb = *(const float4*)&b1[cb];
      int slot_base = cb >> 3;
      int half = (g & 1) * 4;
#pragma unroll
      for (int nf = 0; nf < 4; ++nf) {
        int m = nf * 16 + l15;
        f32x4 a = acc1[mf][nf];
        us4 o;
        o.x = f2bf(fmaxf(s1 * a[0] + bb.x, 0.f));
        o.y = f2bf(fmaxf(s1 * a[1] + bb.y, 0.f));
        o.z = f2bf(fmaxf(s1 * a[2] + bb.z, 0.f));
        o.w = f2bf(fmaxf(s1 * a[3] + bb.w, 0.f));
        int slot = slot_base ^ (m & 7);
        *(us4*)&hs[m * 512 + slot * 8 + half] = o;
      }
    }
    if (i + 1 < TILES) stagex((i + 1) & 1);   // xv(tile i+1) -> LDS
    if (i + 2 < TILES) loadxv(tbase + i + 2); // issue; in flight ~2 phases
    asm volatile("s_waitcnt lgkmcnt(0)" ::: "memory");
    __builtin_amdgcn_s_barrier();   // publish hs(i), xs[i+1]

    // ================= L2: acc2 = W2r * hs^T (K=512) =======================
#pragma unroll
    for (int a = 0; a < 2; ++a)
#pragma unroll
      for (int b = 0; b < 4; ++b) acc2[a][b] = zero4;
    {
      bf16x8 bh[2][4];
#pragma unroll
      for (int nf = 0; nf < 4; ++nf) {
        int m = nf * 16 + l15;
        bh[0][nf] = *(const bf16x8*)&hs[m * 512 + (g ^ (m & 7)) * 8];
      }
#pragma unroll
      for (int kk = 0; kk < 16; ++kk) {
        if (kk + 1 < 16) {
#pragma unroll
          for (int nf = 0; nf < 4; ++nf) {
            int m = nf * 16 + l15;
            int slot = ((kk + 1) * 4 + g) ^ (m & 7);
            bh[(kk + 1) & 1][nf] = *(const bf16x8*)&hs[m * 512 + slot * 8];
          }
        }
#pragma unroll
        for (int nf = 0; nf < 4; ++nf) {
          acc2[0][nf] = __builtin_amdgcn_mfma_f32_16x16x32_bf16(w2r[0][kk], bh[kk & 1][nf], acc2[0][nf], 0, 0, 0);
          acc2[1][nf] = __builtin_amdgcn_mfma_f32_16x16x32_bf16(w2r[1][kk], bh[kk & 1][nf], acc2[1][nf], 0, 0, 0);
        }
      }
    }
    // ===== epi2: out stores (fire and forget; never drained) ===============
    {
      const long row0 = (tbase + i) * BM;
#pragma unroll
      for (int mf = 0; mf < 2; ++mf) {
        int nb = 32 * wv + 16 * mf + 4 * g;
        float4 bb = *(const float4*)&b2[nb];
#pragma unroll
        for (int nf = 0; nf < 4; ++nf) {
          int m = nf * 16 + l15;
          f32x4 a = acc2[mf][nf];
          float4 o;
          o.x = s2 * a[0] + bb.x;
          o.y = s2 * a[1] + bb.y;
          o.z = s2 * a[2] + bb.z;
          o.w = s2 * a[3] + bb.w;
          *(float4*)&out[(row0 + m) * D_OUT + nb] = o;
        }
      }
    }
  }
}

extern "C" void kernel_launch(void* const* d_in, const int* in_sizes, int n_in,
                              void* d_out, int out_size, void* d_ws, size_t ws_size,
                              hipStream_t stream) {
  const float* x  = (const float*)d_in[0];
  const float* W1 = (const float*)d_in[1];
  const float* b1 = (const float*)d_in[2];
  const float* W2 = (const float*)d_in[3];
  const float* b2 = (const float*)d_in[4];
  float* out = (float*)d_out;

  double* part = (double*)d_ws;
  float* fsc = (float*)((char*)d_ws + 128);
  unsigned short* w1c = (unsigned short*)((char*)d_ws + 1024);
  unsigned short* w2c = (unsigned short*)((char*)d_ws + 1024 + D_HID * D_IN * 2);

  int Brows = in_sizes[0] / D_IN;     // 262144
  int nblk = Brows / (BM * TILES);    // 256

  partial_abs_kernel<<<dim3(16), dim3(1024), 0, stream>>>(W1, W2, part);
  quant_kernel<<<dim3(256), dim3(256), 0, stream>>>(W1, W2, part, w1c, w2c, fsc);
  fused_mlp<<<dim3(nblk), dim3(512), 0, stream>>>(x, b1, b2, w1c, w2c, fsc, out);
}